// Round 1
// baseline (519.327 us; speedup 1.0000x reference)
//
#include <hip/hip_runtime.h>
#include <stdint.h>

#define N_ANCH 102400
#define FMP 320
#define NUM_CLASSES 80
#define K_TOP 1000
#define NMS_T 0.6f
#define SC_CLAMP 6.907755278982137f
#define IMGF 1280.0f

// ---- workspace layout (bytes) ----
#define OFF_SCORES   0u          // f32[102400]
#define OFF_LABELS   409600u     // u32[102400]
#define OFF_HIST     819200u     // u32[65536]   (meta follows contiguously)
#define OFF_META     1081344u    // u32[64]  [0]=cutoff bin, [2]=candidate counter
#define OFF_KEYS     1081600u    // u64[8192]
#define OFF_BOXES    1147136u    // f32[4000]  (16B aligned)
#define OFF_LAB1K    1163136u    // u32[1000]
#define OFF_MASK     1167136u    // u64[16000]

__device__ __forceinline__ float sigf(float x) {
    return 1.0f / (1.0f + expf(-x));
}

// K0: zero hist (65536) + meta (64) — contiguous
__global__ __launch_bounds__(256) void k_zero(uint32_t* hist) {
    int i = blockIdx.x * 256 + threadIdx.x;
    if (i < 65536 + 64) hist[i] = 0u;
}

// K1: per-anchor fused score + argmax (wave per anchor) + histogram
__global__ __launch_bounds__(256) void k_scores(const float* __restrict__ hmp,
                                                const float* __restrict__ iou,
                                                float* __restrict__ scores,
                                                uint32_t* __restrict__ labels,
                                                uint32_t* __restrict__ hist) {
    int a    = (blockIdx.x * 256 + threadIdx.x) >> 6;   // anchor = global wave id
    int lane = threadIdx.x & 63;
    float si = sigf(iou[a]);
    const float* row = hmp + (size_t)a * NUM_CLASSES;
    // fused value per class, exactly as reference: sqrt(sig(h)*sig(iou))
    float f1 = sqrtf(sigf(row[lane]) * si);
    int   c1 = lane;
    if (lane < 16) {
        float f2 = sqrtf(sigf(row[64 + lane]) * si);
        if (f2 > f1) { f1 = f2; c1 = 64 + lane; }   // tie keeps smaller class
    }
    for (int off = 32; off; off >>= 1) {
        float of = __shfl_down(f1, off);
        int   oc = __shfl_down(c1, off);
        if (of > f1 || (of == f1 && oc < c1)) { f1 = of; c1 = oc; }
    }
    if (lane == 0) {
        scores[a] = f1;
        labels[a] = (uint32_t)c1;
        atomicAdd(&hist[__float_as_uint(f1) >> 16], 1u);
    }
}

// K2: find 16-bit cutoff bin (largest C with count(bits16 >= C) >= 1000)
__global__ __launch_bounds__(1024) void k_cutoff(const uint32_t* __restrict__ hist,
                                                 uint32_t* __restrict__ meta) {
    __shared__ uint32_t part[1024];
    int t = threadIdx.x;
    uint32_t s = 0;
    for (int b = 0; b < 64; ++b) s += hist[t * 64 + b];
    part[t] = s;
    __syncthreads();
    for (int off = 1; off < 1024; off <<= 1) {
        uint32_t v = part[t] + ((t + off < 1024) ? part[t + off] : 0u);
        __syncthreads();
        part[t] = v;
        __syncthreads();
    }
    uint32_t inc   = part[t];
    uint32_t above = (t < 1023) ? part[t + 1] : 0u;
    if (above < K_TOP && inc >= K_TOP) {
        uint32_t cnt = above;
        for (int b = t * 64 + 63; b >= t * 64; --b) {
            cnt += hist[b];
            if (cnt >= K_TOP) { meta[0] = (uint32_t)b; break; }
        }
    }
}

// K3: collect candidate keys (score_bits<<32 | ~index)
__global__ __launch_bounds__(256) void k_collect(const float* __restrict__ scores,
                                                 uint32_t* __restrict__ meta,
                                                 uint64_t* __restrict__ keys) {
    int i = blockIdx.x * 256 + threadIdx.x;
    if (i >= N_ANCH) return;
    uint32_t bits = __float_as_uint(scores[i]);
    if ((bits >> 16) >= meta[0]) {
        uint32_t pos = atomicAdd(&meta[2], 1u);
        if (pos < 8192)
            keys[pos] = ((uint64_t)bits << 32) | (uint64_t)(0xFFFFFFFFu - (uint32_t)i);
    }
}

// K4: single-block bitonic sort (descending) + gather/decode epilogue
__global__ __launch_bounds__(1024) void k_sort(const uint64_t* __restrict__ keys,
                                               const uint32_t* __restrict__ meta,
                                               const uint32_t* __restrict__ labels,
                                               const float* __restrict__ reg,
                                               float* __restrict__ out,
                                               float* __restrict__ boxes,
                                               uint32_t* __restrict__ lab1k) {
    __shared__ uint64_t sm[8192];
    int t = threadIdx.x;
    uint32_t M = meta[2];
    if (M > 8192u) M = 8192u;
    uint32_t S = 1024;
    while (S < M) S <<= 1;
    for (uint32_t i = t; i < S; i += 1024) sm[i] = (i < M) ? keys[i] : 0ull;
    __syncthreads();
    for (uint32_t k = 2; k <= S; k <<= 1) {
        for (uint32_t j = k >> 1; j > 0; j >>= 1) {
            for (uint32_t i = t; i < S; i += 1024) {
                uint32_t l = i ^ j;
                if (l > i) {
                    uint64_t a = sm[i], b = sm[l];
                    bool asc = (i & k) != 0;      // top level -> descending overall
                    if (asc ? (a > b) : (a < b)) { sm[i] = b; sm[l] = a; }
                }
            }
            __syncthreads();
        }
    }
    if (t < K_TOP) {
        uint64_t key   = sm[t];
        uint32_t sbits = (uint32_t)(key >> 32);
        uint32_t idx   = 0xFFFFFFFFu - (uint32_t)(key & 0xFFFFFFFFull);
        float score = __uint_as_float(sbits);
        uint32_t lab = labels[idx];
        out[t]          = score;
        out[K_TOP + t]  = (float)lab;
        lab1k[t]        = lab;
        float ax = (float)(idx % FMP);
        float ay = (float)(idx / FMP);
        float4 rr = ((const float4*)reg)[idx];
        float e0 = expf(fminf(rr.x, SC_CLAMP));
        float e1 = expf(fminf(rr.y, SC_CLAMP));
        float e2 = expf(fminf(rr.z, SC_CLAMP));
        float e3 = expf(fminf(rr.w, SC_CLAMP));
        float x1 = fminf(fmaxf((ax - e0) * 4.0f / IMGF, 0.0f), 1.0f);
        float y1 = fminf(fmaxf((ay - e1) * 4.0f / IMGF, 0.0f), 1.0f);
        float x2 = fminf(fmaxf((ax + e2) * 4.0f / IMGF, 0.0f), 1.0f);
        float y2 = fminf(fmaxf((ay + e3) * 4.0f / IMGF, 0.0f), 1.0f);
        out[2 * K_TOP + t * 4 + 0] = x1;
        out[2 * K_TOP + t * 4 + 1] = y1;
        out[2 * K_TOP + t * 4 + 2] = x2;
        out[2 * K_TOP + t * 4 + 3] = y2;
        boxes[t * 4 + 0] = x1;
        boxes[t * 4 + 1] = y1;
        boxes[t * 4 + 2] = x2;
        boxes[t * 4 + 3] = y2;
    }
}

// K5: suppress bitmask rows (only j > i bits), grid (16 words, 1000 rows)
__global__ __launch_bounds__(64) void k_mask(const float* __restrict__ boxes,
                                             const uint32_t* __restrict__ lab1k,
                                             uint64_t* __restrict__ mask) {
    int i = blockIdx.y;
    int w = blockIdx.x;
    int lane = threadIdx.x;
    int j = w * 64 + lane;
    float4 bi = ((const float4*)boxes)[i];
    uint32_t li = lab1k[i];
    bool sup = false;
    if (j < K_TOP && j > i) {
        float4 bj = ((const float4*)boxes)[j];
        float areai = (bi.z - bi.x) * (bi.w - bi.y);
        float areaj = (bj.z - bj.x) * (bj.w - bj.y);
        float xx1 = fmaxf(bi.x, bj.x);
        float yy1 = fmaxf(bi.y, bj.y);
        float xx2 = fminf(bi.z, bj.z);
        float yy2 = fminf(bi.w, bj.w);
        float ww = fmaxf(1e-10f, xx2 - xx1);
        float hh = fmaxf(1e-10f, yy2 - yy1);
        float inter = ww * hh;
        float iouv = inter / (areai + areaj - inter + 1e-10f);
        sup = (iouv > NMS_T) && (li == lab1k[j]);
    }
    unsigned long long m = __ballot(sup);
    if (lane == 0) mask[i * 16 + w] = (uint64_t)m;
}

// K6: sequential greedy scan, one wave (16 active lanes hold the remv bitset)
__global__ __launch_bounds__(64) void k_nms(const uint64_t* __restrict__ mask,
                                            float* __restrict__ out) {
    int lane = threadIdx.x;
    unsigned long long remv = 0ull;
    unsigned long long nxt = (lane < 16) ? mask[lane] : 0ull;
    for (int i = 0; i < K_TOP; ++i) {
        unsigned long long cur = nxt;
        if (i + 1 < K_TOP) nxt = (lane < 16) ? mask[(size_t)(i + 1) * 16 + lane] : 0ull;
        unsigned long long rv = __shfl(remv, i >> 6);
        if (!((rv >> (i & 63)) & 1ull)) {
            if (lane < 16) remv |= cur;
        }
    }
    if (lane < 16) {
        for (int b = 0; b < 64; ++b) {
            int j = lane * 64 + b;
            if (j < K_TOP) out[6 * K_TOP + j] = ((remv >> b) & 1ull) ? 0.0f : 1.0f;
        }
    }
}

extern "C" void kernel_launch(void* const* d_in, const int* in_sizes, int n_in,
                              void* d_out, int out_size, void* d_ws, size_t ws_size,
                              hipStream_t stream) {
    const float* hmp = (const float*)d_in[0];
    const float* reg = (const float*)d_in[1];
    const float* iou = (const float*)d_in[2];
    float* out = (float*)d_out;
    char* ws = (char*)d_ws;

    float*    scores = (float*)(ws + OFF_SCORES);
    uint32_t* labels = (uint32_t*)(ws + OFF_LABELS);
    uint32_t* hist   = (uint32_t*)(ws + OFF_HIST);
    uint32_t* meta   = (uint32_t*)(ws + OFF_META);
    uint64_t* keys   = (uint64_t*)(ws + OFF_KEYS);
    float*    boxes  = (float*)(ws + OFF_BOXES);
    uint32_t* lab1k  = (uint32_t*)(ws + OFF_LAB1K);
    uint64_t* mask   = (uint64_t*)(ws + OFF_MASK);

    k_zero<<<dim3((65536 + 64 + 255) / 256), dim3(256), 0, stream>>>(hist);
    k_scores<<<dim3(N_ANCH / 4), dim3(256), 0, stream>>>(hmp, iou, scores, labels, hist);
    k_cutoff<<<dim3(1), dim3(1024), 0, stream>>>(hist, meta);
    k_collect<<<dim3((N_ANCH + 255) / 256), dim3(256), 0, stream>>>(scores, meta, keys);
    k_sort<<<dim3(1), dim3(1024), 0, stream>>>(keys, meta, labels, reg, out, boxes, lab1k);
    k_mask<<<dim3(16, K_TOP), dim3(64), 0, stream>>>(boxes, lab1k, mask);
    k_nms<<<dim3(1), dim3(64), 0, stream>>>(mask, out);
}

// Round 2
// 339.725 us; speedup vs baseline: 1.5287x; 1.5287x over previous
//
#include <hip/hip_runtime.h>
#include <stdint.h>

#define N_ANCH 102400
#define FMP 320
#define NUM_CLASSES 80
#define K_TOP 1000
#define NMS_T 0.6f
#define SC_CLAMP 6.907755278982137f
#define IMGF 1280.0f

// ---- workspace layout (bytes) ----
#define OFF_SCORES   0u          // f32[102400]
#define OFF_LABELS   409600u     // u32[102400]
#define OFF_HIST     819200u     // u32[65536]   (meta follows contiguously)
#define OFF_META     1081344u    // u32[64]  [0]=cutoff bin, [2]=candidate counter
#define OFF_KEYS     1081600u    // u64[8192]
#define OFF_BOXES    1147136u    // f32[4000]  (16B aligned)
#define OFF_LAB1K    1163136u    // u32[1000]
#define OFF_MASK     1167136u    // u64[16000]

__device__ __forceinline__ float sigf(float x) {
    return 1.0f / (1.0f + expf(-x));
}

// K0: zero hist (65536) + meta (64) — contiguous
__global__ __launch_bounds__(256) void k_zero(uint32_t* hist) {
    int i = blockIdx.x * 256 + threadIdx.x;
    if (i < 65536 + 64) hist[i] = 0u;
}

// K1: fused score + argmax. 4 threads per anchor, 5 float4 loads per thread.
// Classes for thread q, vec j: 16j + 4q + {0..3} (ascending within thread).
__global__ __launch_bounds__(256) void k_scores(const float* __restrict__ hmp,
                                                const float* __restrict__ iou,
                                                float* __restrict__ scores,
                                                uint32_t* __restrict__ labels,
                                                uint32_t* __restrict__ hist) {
    int gid = blockIdx.x * 256 + threadIdx.x;
    int a = gid >> 2;
    int q = gid & 3;
    float si = sigf(iou[a]);
    const float4* row4 = (const float4*)hmp + (size_t)a * 20 + q;
    float4 v[5];
#pragma unroll
    for (int j = 0; j < 5; ++j) v[j] = row4[j * 4];
    float best = -1.0f;
    int bc = 0;
#pragma unroll
    for (int j = 0; j < 5; ++j) {
        int cb = j * 16 + q * 4;
        float f;
        f = sqrtf(sigf(v[j].x) * si); if (f > best) { best = f; bc = cb; }
        f = sqrtf(sigf(v[j].y) * si); if (f > best) { best = f; bc = cb + 1; }
        f = sqrtf(sigf(v[j].z) * si); if (f > best) { best = f; bc = cb + 2; }
        f = sqrtf(sigf(v[j].w) * si); if (f > best) { best = f; bc = cb + 3; }
    }
    // reduce across the 4 lanes of this anchor (tie -> smaller class)
#pragma unroll
    for (int off = 1; off <= 2; off <<= 1) {
        float of = __shfl_xor(best, off);
        int   oc = __shfl_xor(bc, off);
        if (of > best || (of == best && oc < bc)) { best = of; bc = oc; }
    }
    if (q == 0) {
        scores[a] = best;
        labels[a] = (uint32_t)bc;
        atomicAdd(&hist[__float_as_uint(best) >> 16], 1u);
    }
}

// K2: find 16-bit cutoff bin (largest C with count(bits16 >= C) >= 1000)
__global__ __launch_bounds__(1024) void k_cutoff(const uint32_t* __restrict__ hist,
                                                 uint32_t* __restrict__ meta) {
    __shared__ uint32_t part[1024];
    int t = threadIdx.x;
    uint32_t s = 0;
    for (int b = 0; b < 64; ++b) s += hist[t * 64 + b];
    part[t] = s;
    __syncthreads();
    for (int off = 1; off < 1024; off <<= 1) {
        uint32_t v = part[t] + ((t + off < 1024) ? part[t + off] : 0u);
        __syncthreads();
        part[t] = v;
        __syncthreads();
    }
    uint32_t inc   = part[t];
    uint32_t above = (t < 1023) ? part[t + 1] : 0u;
    if (above < K_TOP && inc >= K_TOP) {
        uint32_t cnt = above;
        for (int b = t * 64 + 63; b >= t * 64; --b) {
            cnt += hist[b];
            if (cnt >= K_TOP) { meta[0] = (uint32_t)b; break; }
        }
    }
}

// K3: collect candidate keys (score_bits<<32 | ~index)
__global__ __launch_bounds__(256) void k_collect(const float* __restrict__ scores,
                                                 uint32_t* __restrict__ meta,
                                                 uint64_t* __restrict__ keys) {
    int i = blockIdx.x * 256 + threadIdx.x;
    if (i >= N_ANCH) return;
    uint32_t bits = __float_as_uint(scores[i]);
    if ((bits >> 16) >= meta[0]) {
        uint32_t pos = atomicAdd(&meta[2], 1u);
        if (pos < 8192)
            keys[pos] = ((uint64_t)bits << 32) | (uint64_t)(0xFFFFFFFFu - (uint32_t)i);
    }
}

// K4: brute-force exact ranking (keys unique) + gather/decode epilogue.
// 64 blocks x 64 lanes; block b ranks candidates [64b, 64b+64).
__global__ __launch_bounds__(64) void k_rank(const uint64_t* __restrict__ keys,
                                             const uint32_t* __restrict__ meta,
                                             const uint32_t* __restrict__ labels,
                                             const float* __restrict__ reg,
                                             float* __restrict__ out,
                                             float* __restrict__ boxes,
                                             uint32_t* __restrict__ lab1k) {
    __shared__ uint64_t sk[4096];
    int lane = threadIdx.x;
    uint32_t M = meta[2];
    if (M > 4096u) M = 4096u;
    if ((uint32_t)(blockIdx.x * 64) >= M) return;
    for (uint32_t i = lane; i < M; i += 64) sk[i] = keys[i];
    __syncthreads();
    int c = blockIdx.x * 64 + lane;
    if ((uint32_t)c >= M) return;
    uint64_t mykey = sk[c];
    uint32_t rank = 0;
    uint32_t i = 0;
    for (; i + 8 <= M; i += 8) {
#pragma unroll
        for (int u = 0; u < 8; ++u) rank += (sk[i + u] > mykey) ? 1u : 0u;
    }
    for (; i < M; ++i) rank += (sk[i] > mykey) ? 1u : 0u;
    if (rank >= K_TOP) return;
    int t = (int)rank;
    uint32_t sbits = (uint32_t)(mykey >> 32);
    uint32_t idx   = 0xFFFFFFFFu - (uint32_t)(mykey & 0xFFFFFFFFull);
    float score = __uint_as_float(sbits);
    uint32_t lab = labels[idx];
    out[t]         = score;
    out[K_TOP + t] = (float)lab;
    lab1k[t]       = lab;
    float ax = (float)(idx % FMP);
    float ay = (float)(idx / FMP);
    float4 rr = ((const float4*)reg)[idx];
    float e0 = expf(fminf(rr.x, SC_CLAMP));
    float e1 = expf(fminf(rr.y, SC_CLAMP));
    float e2 = expf(fminf(rr.z, SC_CLAMP));
    float e3 = expf(fminf(rr.w, SC_CLAMP));
    float x1 = fminf(fmaxf((ax - e0) * 4.0f / IMGF, 0.0f), 1.0f);
    float y1 = fminf(fmaxf((ay - e1) * 4.0f / IMGF, 0.0f), 1.0f);
    float x2 = fminf(fmaxf((ax + e2) * 4.0f / IMGF, 0.0f), 1.0f);
    float y2 = fminf(fmaxf((ay + e3) * 4.0f / IMGF, 0.0f), 1.0f);
    out[2 * K_TOP + t * 4 + 0] = x1;
    out[2 * K_TOP + t * 4 + 1] = y1;
    out[2 * K_TOP + t * 4 + 2] = x2;
    out[2 * K_TOP + t * 4 + 3] = y2;
    boxes[t * 4 + 0] = x1;
    boxes[t * 4 + 1] = y1;
    boxes[t * 4 + 2] = x2;
    boxes[t * 4 + 3] = y2;
}

// K5: suppress bitmask rows (only j > i bits), grid (16 words, 1000 rows)
__global__ __launch_bounds__(64) void k_mask(const float* __restrict__ boxes,
                                             const uint32_t* __restrict__ lab1k,
                                             uint64_t* __restrict__ mask) {
    int i = blockIdx.y;
    int w = blockIdx.x;
    int lane = threadIdx.x;
    int j = w * 64 + lane;
    float4 bi = ((const float4*)boxes)[i];
    uint32_t li = lab1k[i];
    bool sup = false;
    if (j < K_TOP && j > i) {
        float4 bj = ((const float4*)boxes)[j];
        float areai = (bi.z - bi.x) * (bi.w - bi.y);
        float areaj = (bj.z - bj.x) * (bj.w - bj.y);
        float xx1 = fmaxf(bi.x, bj.x);
        float yy1 = fmaxf(bi.y, bj.y);
        float xx2 = fminf(bi.z, bj.z);
        float yy2 = fminf(bi.w, bj.w);
        float ww = fmaxf(1e-10f, xx2 - xx1);
        float hh = fmaxf(1e-10f, yy2 - yy1);
        float inter = ww * hh;
        float iouv = inter / (areai + areaj - inter + 1e-10f);
        sup = (iouv > NMS_T) && (li == lab1k[j]);
    }
    unsigned long long m = __ballot(sup);
    if (lane == 0) mask[i * 16 + w] = (uint64_t)m;
}

// K6: greedy scan. D (the active chunk's suppression word) is wave-uniform:
// diagonal-word loads use a uniform address (-> s_load) and chunk-initial D
// comes from readlane (-> SGPR), so the serial chain is scalar ALU.
// Lane l (<16) accumulates remv word l off-chain.
__global__ __launch_bounds__(64) void k_nms(const uint64_t* __restrict__ mask,
                                            float* __restrict__ out) {
    int lane = threadIdx.x;
    uint64_t remv = 0ull;
    for (int w = 0; w < 16; ++w) {
        uint32_t dlo = __builtin_amdgcn_readlane((uint32_t)remv, w);
        uint32_t dhi = __builtin_amdgcn_readlane((uint32_t)(remv >> 32), w);
        uint64_t D = ((uint64_t)dhi << 32) | dlo;
        for (int b0 = 0; b0 < 64; b0 += 8) {
            uint64_t mv[8], cv[8];
#pragma unroll
            for (int u = 0; u < 8; ++u) {
                int i = w * 64 + b0 + u;
                int ri = (i < K_TOP) ? i : 0;
                uint64_t valid = (i < K_TOP) ? ~0ull : 0ull;
                mv[u] = mask[(size_t)ri * 16 + w] & valid;                       // uniform
                cv[u] = ((lane < 16) ? mask[(size_t)ri * 16 + lane] : 0ull) & valid;
            }
#pragma unroll
            for (int u = 0; u < 8; ++u) {
                int b = b0 + u;
                uint64_t sup = (D >> b) & 1ull;          // scalar chain
                uint64_t sel = sup ? 0ull : ~0ull;
                D    |= mv[u] & sel;
                remv |= cv[u] & sel;
            }
        }
    }
    // coalesced keep write
    for (int g = 0; g < 16; ++g) {
        uint64_t rg = __shfl(remv, g);
        int j = g * 64 + lane;
        if (j < K_TOP) out[6 * K_TOP + j] = ((rg >> lane) & 1ull) ? 0.0f : 1.0f;
    }
}

extern "C" void kernel_launch(void* const* d_in, const int* in_sizes, int n_in,
                              void* d_out, int out_size, void* d_ws, size_t ws_size,
                              hipStream_t stream) {
    const float* hmp = (const float*)d_in[0];
    const float* reg = (const float*)d_in[1];
    const float* iou = (const float*)d_in[2];
    float* out = (float*)d_out;
    char* ws = (char*)d_ws;

    float*    scores = (float*)(ws + OFF_SCORES);
    uint32_t* labels = (uint32_t*)(ws + OFF_LABELS);
    uint32_t* hist   = (uint32_t*)(ws + OFF_HIST);
    uint32_t* meta   = (uint32_t*)(ws + OFF_META);
    uint64_t* keys   = (uint64_t*)(ws + OFF_KEYS);
    float*    boxes  = (float*)(ws + OFF_BOXES);
    uint32_t* lab1k  = (uint32_t*)(ws + OFF_LAB1K);
    uint64_t* mask   = (uint64_t*)(ws + OFF_MASK);

    k_zero<<<dim3((65536 + 64 + 255) / 256), dim3(256), 0, stream>>>(hist);
    k_scores<<<dim3(N_ANCH * 4 / 256), dim3(256), 0, stream>>>(hmp, iou, scores, labels, hist);
    k_cutoff<<<dim3(1), dim3(1024), 0, stream>>>(hist, meta);
    k_collect<<<dim3((N_ANCH + 255) / 256), dim3(256), 0, stream>>>(scores, meta, keys);
    k_rank<<<dim3(64), dim3(64), 0, stream>>>(keys, meta, labels, reg, out, boxes, lab1k);
    k_mask<<<dim3(16, K_TOP), dim3(64), 0, stream>>>(boxes, lab1k, mask);
    k_nms<<<dim3(1), dim3(64), 0, stream>>>(mask, out);
}